// Round 2
// baseline (505.670 us; speedup 1.0000x reference)
//
#include <hip/hip_runtime.h>
#include <hip/hip_bf16.h>
#include <stdint.h>

#define NROWS 131072
#define EPSBN 1e-5f
#define LEAKK 0.33f

typedef __bf16 bf16x8_t __attribute__((ext_vector_type(8)));
typedef __bf16 bf16x4_t __attribute__((ext_vector_type(4)));
typedef float  f32x4_t  __attribute__((ext_vector_type(4)));

__device__ __forceinline__ float leaky_f(float x) { return fmaxf(x, LEAKK * x); }

// Gather-GEMM conv: out[n,d] = sum_k mask[n,k] * sum_c src[idx[n,k],c] * w[k,c,d]
// wt layout: [9][64 d][64 c] bf16 (pre-transposed).  Also accumulates per-channel
// sum / sumsq of the fp32 outputs into stat_out[0..63] / stat_out[64..127].
__global__ __launch_bounds__(256, 3) void conv_kernel(
    const __bf16* __restrict__ src, const int* __restrict__ nidx,
    const unsigned char* __restrict__ nmask, const __bf16* __restrict__ wt,
    __bf16* __restrict__ dst_h, float* __restrict__ dst_f,
    float* __restrict__ stat_out)
{
    __shared__ __bf16 gbuf[256][72];   // 144B row stride: conflict-free b128
    __shared__ __bf16 wbuf[64][72];
    __shared__ float  red[128];

    const int tid  = threadIdx.x;
    const int lane = tid & 63;
    const int wv   = tid >> 6;
    const int quad = lane >> 4;
    const int l15  = lane & 15;
    const int row0 = blockIdx.x << 8;

    if (tid < 128) red[tid] = 0.f;

    f32x4_t acc[4][4];
#pragma unroll
    for (int mt = 0; mt < 4; ++mt)
#pragma unroll
        for (int nt = 0; nt < 4; ++nt)
            acc[mt][nt] = (f32x4_t){0.f, 0.f, 0.f, 0.f};

    for (int k = 0; k < 9; ++k) {
        __syncthreads();
        // stage weight slab k: 64x64 bf16, coalesced read, conflict-free write
        {
            const uint4* wsrc = (const uint4*)(wt + ((size_t)k << 12));
#pragma unroll
            for (int i = 0; i < 2; ++i) {
                int item = tid + (i << 8);
                int d = item >> 3, blk = item & 7;
                uint4 v = wsrc[item];
                *(uint4*)(&wbuf[d][blk << 3]) = v;
            }
        }
        // stage gathered rows: 2 threads per row, 64B each (4x uint4)
#pragma unroll
        for (int i = 0; i < 2; ++i) {
            int item = tid + (i << 8);
            int r = item >> 1, s = item & 1;
            int grow = row0 + r;
            int ni = nidx[grow * 9 + k];
            unsigned char mk = nmask[grow * 9 + k];
            uint4 v0 = {0,0,0,0}, v1 = {0,0,0,0}, v2 = {0,0,0,0}, v3 = {0,0,0,0};
            if (mk) {
                const uint4* sp = (const uint4*)(src + ((size_t)ni << 6) + (s << 5));
                v0 = sp[0]; v1 = sp[1]; v2 = sp[2]; v3 = sp[3];
            }
            __bf16* gdst = &gbuf[r][s << 5];
            *(uint4*)(gdst)      = v0;
            *(uint4*)(gdst + 8)  = v1;
            *(uint4*)(gdst + 16) = v2;
            *(uint4*)(gdst + 24) = v3;
        }
        __syncthreads();
#pragma unroll
        for (int ks = 0; ks < 2; ++ks) {
            bf16x8_t af[4], bfr[4];
#pragma unroll
            for (int mt = 0; mt < 4; ++mt)
                af[mt] = *(const bf16x8_t*)(&gbuf[(wv << 6) + (mt << 4) + l15][(ks << 5) + (quad << 3)]);
#pragma unroll
            for (int nt = 0; nt < 4; ++nt)
                bfr[nt] = *(const bf16x8_t*)(&wbuf[(nt << 4) + l15][(ks << 5) + (quad << 3)]);
#pragma unroll
            for (int mt = 0; mt < 4; ++mt)
#pragma unroll
                for (int nt = 0; nt < 4; ++nt)
                    acc[mt][nt] = __builtin_amdgcn_mfma_f32_16x16x32_bf16(
                        af[mt], bfr[nt], acc[mt][nt], 0, 0, 0);
        }
    }

    // store outputs (D layout: row = quad*4+reg, col = lane&15)
#pragma unroll
    for (int mt = 0; mt < 4; ++mt) {
        int rowb = row0 + (wv << 6) + (mt << 4) + (quad << 2);
#pragma unroll
        for (int nt = 0; nt < 4; ++nt) {
            int col = (nt << 4) + l15;
#pragma unroll
            for (int r = 0; r < 4; ++r) {
                float v = acc[mt][nt][r];
                size_t o = ((size_t)(rowb + r) << 6) + col;
                if (dst_f) dst_f[o] = v;
                else       dst_h[o] = (__bf16)v;
            }
        }
    }
    // per-channel stats: lane-local 16 rows -> quad shuffle -> LDS atomics -> global
#pragma unroll
    for (int nt = 0; nt < 4; ++nt) {
        float s = 0.f, q = 0.f;
#pragma unroll
        for (int mt = 0; mt < 4; ++mt)
#pragma unroll
            for (int r = 0; r < 4; ++r) { float v = acc[mt][nt][r]; s += v; q += v * v; }
        s += __shfl_xor(s, 16); s += __shfl_xor(s, 32);
        q += __shfl_xor(q, 16); q += __shfl_xor(q, 32);
        if (lane < 16) {
            atomicAdd(&red[(nt << 4) + lane], s);
            atomicAdd(&red[64 + (nt << 4) + lane], q);
        }
    }
    __syncthreads();
    if (tid < 128) atomicAdd(&stat_out[tid], red[tid]);
}

// in-place y = leaky(bn(y)) on bf16, params computed from stats per-workgroup
__global__ __launch_bounds__(256) void bnact_kernel(
    __bf16* __restrict__ y, const float* __restrict__ stat,
    const float* __restrict__ gamma, const float* __restrict__ beta)
{
    __shared__ float sc[64], sh[64];
    int tid = threadIdx.x;
    if (tid < 64) {
        float m = stat[tid] * (1.f / NROWS);
        float v = stat[64 + tid] * (1.f / NROWS) - m * m;
        float s = gamma[tid] * rsqrtf(v + EPSBN);
        sc[tid] = s;
        sh[tid] = beta[tid] - m * s;
    }
    __syncthreads();
    size_t base = ((((size_t)blockIdx.x << 8) | tid) << 3);
    int c0 = (int)(base & 63);
    bf16x8_t hv = *(bf16x8_t*)(y + base);
#pragma unroll
    for (int j = 0; j < 8; ++j) {
        float f = (float)hv[j];
        f = leaky_f(f * sc[c0 + j] + sh[c0 + j]);
        hv[j] = (__bf16)f;
    }
    *(bf16x8_t*)(y + base) = hv;
}

// x_new = leaky(bn2(z) + x); writes fp32 (+bf16 mirror) or final fp32 output
__global__ __launch_bounds__(256) void resid_kernel(
    const float* __restrict__ z, const float* __restrict__ xin,
    float* __restrict__ xf, __bf16* __restrict__ xh, float* __restrict__ dout,
    const float* __restrict__ stat, const float* __restrict__ gamma,
    const float* __restrict__ beta, int isfinal)
{
    __shared__ float sc[64], sh[64];
    int tid = threadIdx.x;
    if (tid < 64) {
        float m = stat[tid] * (1.f / NROWS);
        float v = stat[64 + tid] * (1.f / NROWS) - m * m;
        float s = gamma[tid] * rsqrtf(v + EPSBN);
        sc[tid] = s;
        sh[tid] = beta[tid] - m * s;
    }
    __syncthreads();
    size_t base = ((((size_t)blockIdx.x << 8) | tid) << 2);
    int c0 = (int)(base & 63);
    float4 zv = *(const float4*)(z + base);
    float4 xv = *(const float4*)(xin + base);
    float o0 = leaky_f(zv.x * sc[c0 + 0] + sh[c0 + 0] + xv.x);
    float o1 = leaky_f(zv.y * sc[c0 + 1] + sh[c0 + 1] + xv.y);
    float o2 = leaky_f(zv.z * sc[c0 + 2] + sh[c0 + 2] + xv.z);
    float o3 = leaky_f(zv.w * sc[c0 + 3] + sh[c0 + 3] + xv.w);
    if (isfinal) {
        *(float4*)(dout + base) = make_float4(o0, o1, o2, o3);
    } else {
        *(float4*)(xf + base) = make_float4(o0, o1, o2, o3);
        bf16x4_t h;
        h[0] = (__bf16)o0; h[1] = (__bf16)o1; h[2] = (__bf16)o2; h[3] = (__bf16)o3;
        *(bf16x4_t*)(xh + base) = h;
    }
}

// once-per-call prep: features->bf16, weights->transposed bf16, zero stats,
// and normalize neighbor_mask to 1 byte/entry regardless of source encoding.
// Encoding detect: center mask (k=4) is always True. Raw byte 13 = mask[1][4]
// under byte-encoding (nonzero), but is padding byte 1 of word 3 under
// int32/float32 encoding (exactly 0).
__global__ __launch_bounds__(256) void prep_kernel(
    const float* __restrict__ feat, const float* __restrict__ w1,
    const float* __restrict__ w2, const unsigned char* __restrict__ mraw,
    __bf16* __restrict__ fh, __bf16* __restrict__ wtp,
    unsigned char* __restrict__ mout, float* __restrict__ stats)
{
    size_t t = ((size_t)blockIdx.x << 8) | threadIdx.x;
    if (t < 1024) stats[t] = 0.f;
    if (t < 1048576) {  // features: 8 floats -> 8 bf16 per thread
        size_t i = t << 3;
        float4 a = *(const float4*)(feat + i);
        float4 b = *(const float4*)(feat + i + 4);
        bf16x8_t h;
        h[0] = (__bf16)a.x; h[1] = (__bf16)a.y; h[2] = (__bf16)a.z; h[3] = (__bf16)a.w;
        h[4] = (__bf16)b.x; h[5] = (__bf16)b.y; h[6] = (__bf16)b.z; h[7] = (__bf16)b.w;
        *(bf16x8_t*)(fh + i) = h;
    }
    if (t < 294912) {   // wtp[cv][b][k][d][c] = w[b][k][c][d]
        int o = (int)t;
        int c = o & 63, d = (o >> 6) & 63;
        int kk = o >> 12;              // 0..71
        int k = kk % 9, bb = (kk / 9) & 3, cv = kk / 36;
        const float* w = cv ? w2 : w1;
        float v = w[((size_t)((bb * 9 + k) * 64 + c) << 6) + d];
        wtp[o] = (__bf16)v;
    }
    if (t < 294912) {   // mask normalize: 4 entries/thread (1179648 total)
        bool bytes_enc = (mraw[13] != 0);
        int i = (int)t << 2;
        uchar4 m;
        if (bytes_enc) {
            uchar4 r = *(const uchar4*)(mraw + i);
            m.x = r.x ? 1 : 0; m.y = r.y ? 1 : 0; m.z = r.z ? 1 : 0; m.w = r.w ? 1 : 0;
        } else {
            const uint4 r = *(const uint4*)(mraw + ((size_t)i << 2));
            m.x = r.x ? 1 : 0; m.y = r.y ? 1 : 0; m.z = r.z ? 1 : 0; m.w = r.w ? 1 : 0;
        }
        *(uchar4*)(mout + i) = m;
    }
}

extern "C" void kernel_launch(void* const* d_in, const int* in_sizes, int n_in,
                              void* d_out, int out_size, void* d_ws, size_t ws_size,
                              hipStream_t stream) {
    const float* feat = (const float*)d_in[0];
    const int* nidx = (const int*)d_in[1];
    const unsigned char* mraw = (const unsigned char*)d_in[2];
    const float* w1 = (const float*)d_in[3];
    const float* g1 = (const float*)d_in[4];
    const float* b1 = (const float*)d_in[5];
    const float* w2 = (const float*)d_in[6];
    const float* g2 = (const float*)d_in[7];
    const float* b2 = (const float*)d_in[8];
    float* out = (float*)d_out;

    char* ws = (char*)d_ws;
    float*  xf    = (float*)ws;                       // 33.55 MB fp32 residual stream
    float*  zb    = (float*)(ws + 33554432);          // 33.55 MB fp32 conv2 out
    __bf16* xh    = (__bf16*)(ws + 67108864);         // 16.78 MB bf16 gather mirror of x
    __bf16* yh    = (__bf16*)(ws + 83886080);         // 16.78 MB bf16 conv1 out / bn1 act
    __bf16* wtp   = (__bf16*)(ws + 100663296);        // 0.59 MB bf16 transposed weights
    float*  stats = (float*)(ws + 101253120);         // 8 stages x 128 floats
    unsigned char* mn = (unsigned char*)(ws + 101257216); // 1.18 MB normalized mask

    prep_kernel<<<4096, 256, 0, stream>>>(feat, w1, w2, mraw, xh, wtp, mn, stats);

    for (int b = 0; b < 4; ++b) {
        // conv1: gather x (bf16) -> y (bf16) + stats[2b]
        conv_kernel<<<512, 256, 0, stream>>>(
            xh, nidx, mn, wtp + (size_t)b * 9 * 4096,
            yh, nullptr, stats + (size_t)(2 * b) * 128);
        // y = leaky(bn1(y)) in place
        bnact_kernel<<<4096, 256, 0, stream>>>(
            yh, stats + (size_t)(2 * b) * 128, g1 + b * 64, b1 + b * 64);
        // conv2: gather y' (bf16) -> z (fp32) + stats[2b+1]
        conv_kernel<<<512, 256, 0, stream>>>(
            yh, nidx, mn, wtp + (size_t)(4 + b) * 9 * 4096,
            nullptr, zb, stats + (size_t)(2 * b + 1) * 128);
        // x = leaky(bn2(z) + x); final block writes d_out (fp32)
        resid_kernel<<<8192, 256, 0, stream>>>(
            zb, (b == 0) ? feat : xf, xf, xh, out,
            stats + (size_t)(2 * b + 1) * 128, g2 + b * 64, b2 + b * 64,
            (b == 3) ? 1 : 0);
    }
}